// Round 11
// baseline (379.094 us; speedup 1.0000x reference)
//
#include <hip/hip_runtime.h>
#include <hip/hip_bf16.h>

#define EPS 1e-6f

typedef float f32x4 __attribute__((ext_vector_type(4)));
typedef float f32x2 __attribute__((ext_vector_type(2)));
typedef __bf16 bf16x8 __attribute__((ext_vector_type(8)));
typedef short short8 __attribute__((ext_vector_type(8)));

static __device__ __forceinline__ short bf16bits(float x) {
    __hip_bfloat16 h = __float2bfloat16(x);
    short s;
    __builtin_memcpy(&s, &h, 2);
    return s;
}

// Inline-asm 16B global load: compiler cannot sink/flatten -> the counted-
// vmcnt pipeline in kC physically exists (T4 recipe).
static __device__ __forceinline__ bf16x8 gload16(const short* p) {
    bf16x8 r;
    asm volatile("global_load_dwordx4 %0, %1, off"
                 : "=&v"(r) : "v"(p) : "memory");
    return r;
}
#define WAITV(N)                                                   \
    do {                                                           \
        asm volatile("s_waitcnt vmcnt(" #N ")" ::: "memory");      \
        __builtin_amdgcn_sched_barrier(0);                         \
    } while (0)

// ---- Kernel A: softmax + P23 (f32) + P01T (f32) + P23s_hi (bf16, swizzled) -
__global__ __launch_bounds__(256) void kA(const float* __restrict__ logits,
                                          const float* __restrict__ y_true,
                                          float* __restrict__ P23,
                                          float* __restrict__ P01T,
                                          short* __restrict__ P23s_hi,
                                          int* __restrict__ label) {
    __shared__ float row[64];
    int b = blockIdx.x, t = threadIdx.x;
    if (t < 64) {
        float x = logits[b * 64 + t];
        float m = x;
        for (int mk = 8; mk >= 1; mk >>= 1) m = fmaxf(m, __shfl_xor(m, mk, 16));
        float e = __expf(x - m);
        float s = e;
        for (int mk = 8; mk >= 1; mk >>= 1) s += __shfl_xor(s, mk, 16);
        row[t] = e / s;
    }
    if (t >= 128 && t < 228) {
        int y = t - 128;
        if (y_true[b * 100 + y] > 0.5f) label[b] = y;
    }
    __syncthreads();
    int hi = t >> 4, lo = t & 15;
    float v01 = row[hi] * row[16 + lo];
    float v23 = row[32 + hi] * row[48 + lo];
    P01T[t * 1024 + b] = v01;
    P23[b * 256 + t] = v23;
    int ts = t ^ ((b & 7) << 3);   // XOR swizzle (matches kC LDS read)
    P23s_hi[b * 256 + ts] = bf16bits(v23);
}

// ---- Kernel B: streaming atomic accumulation -> pyF (fragment layout) ------
// grid (u, colhalf) = 512 blocks x 512 thr (4 row-groups g x 128 cols).
// Rows processed IN ORDER (coalesced, branchless): one ds_add_f32 per row.
// Output pyF in MFMA-B-fragment order: [(kt*8+yt)*512 + lane*8 + i] shorts,
// so kC's B-loads are 1KB-contiguous per wave.
__global__ __launch_bounds__(512, 2) void kB(const float* __restrict__ P01T,
                                             const float* __restrict__ P23,
                                             const int* __restrict__ label,
                                             short* __restrict__ pyF) {
    __shared__ __align__(16) float numy[100 * 132];
    __shared__ __align__(16) float aA[1024];
    __shared__ __align__(8) unsigned char yl[1024];
    __shared__ float numjl[4][128];
    int t = threadIdx.x;
    int u = blockIdx.x >> 1;
    int col0 = (blockIdx.x & 1) << 7;

    for (int i = t; i < 1024; i += 512) {
        yl[i] = (unsigned char)label[i];
        aA[i] = P01T[u * 1024 + i];     // sequential, coalesced
    }
    for (int i = t; i < 100 * 132; i += 512) numy[i] = 0.f;
    __syncthreads();

    int g = t >> 7, tcl = t & 127;
    int tc = col0 + tcl;
    int base = g << 8;                  // 256 rows per group
    float nj = 0.f;

    #pragma unroll 1
    for (int c = 0; c < 32; ++c) {
        int r0 = base + c * 8;
        f32x4 a0 = *(const f32x4*)&aA[r0];
        f32x4 a1 = *(const f32x4*)&aA[r0 + 4];
        uint2 yp = *(const uint2*)&yl[r0];
        #pragma unroll
        for (int k = 0; k < 8; ++k) {
            float pv = P23[(r0 + k) * 256 + tc];     // coalesced stream
            float a = (k < 4) ? a0[k] : a1[k - 4];
            unsigned yw = (k < 4) ? yp.x : yp.y;
            int y = (int)((yw >> ((unsigned)(k & 3) * 8u)) & 255u);
            float f = a * pv;
            nj += f;
            atomicAdd(&numy[y * 132 + tcl], f);      // ds_add_f32, 2-way free
        }
    }
    numjl[g][tcl] = nj;
    __syncthreads();

    // fragment-layout write, fully coalesced u32 stores
    int c0k = col0 >> 5;                // 0 or 4
    for (int it = 0; it < 16; ++it) {
        int idx = it * 512 + t;         // 0..8191 u32 units
        int i2 = idx & 3;
        int lane = (idx >> 2) & 63;
        int yt = (idx >> 8) & 7;
        int kt_l = idx >> 11;           // 0..3
        int l15 = lane & 15, l4 = lane >> 4;
        int y = yt * 16 + l15;
        int jl = kt_l * 32 + l4 * 8 + i2 * 2;
        float v0 = 0.f, v1 = 0.f;
        if (y < 100) {
            float d0 = fmaxf(numjl[0][jl] + numjl[1][jl] + numjl[2][jl] + numjl[3][jl], EPS);
            float d1 = fmaxf(numjl[0][jl + 1] + numjl[1][jl + 1] + numjl[2][jl + 1] + numjl[3][jl + 1], EPS);
            f32x2 nv = *(const f32x2*)&numy[y * 132 + jl];
            v0 = fminf(fmaxf(nv[0], EPS) / d0, 1.0f);
            v1 = fminf(fmaxf(nv[1], EPS) / d1, 1.0f);
        }
        unsigned h0 = (unsigned short)bf16bits(v0);
        unsigned h1 = (unsigned short)bf16bits(v1);
        int kt = u * 8 + c0k + kt_l;
        size_t ei = (size_t)(kt * 8 + yt) * 256 + lane * 4 + i2;   // u32 index
        ((unsigned*)pyF)[ei] = h0 | (h1 << 16);
    }
}

// ---- Kernel C: MFMA GEMM.  part[uspl][y][b] += P01[b,u]*(py_u x P23^T) -----
// block tile: 64b x 128y x 8u; grid = 16 bb x 32 uspl (uspl=bid&31 keeps all
// 16 bb-sharers of an uspl on one XCD residue under %8 round-robin).
// 512 thr = 8 waves (2 wb x 4 wy), wave tile 32b x 32y.
// A = P23 bf16 in LDS (32 KB, swizzled). B = pyF fragments: each load is a
// CONTIGUOUS 1KB per wave (lane*16B) -- no more 16-segment gather.
// Forced asm pipeline: 4 named buffer sets, 3-step lookahead, vmcnt(6).
__global__ __launch_bounds__(512, 2) void kC(const short* __restrict__ P23s_hi,
                                             const float* __restrict__ P01T,
                                             const short* __restrict__ pyF,
                                             float* __restrict__ part) {
    __shared__ short Ahi[64 * 256];
    __shared__ float p01s[8 * 64];
    int t = threadIdx.x;
    int bb = blockIdx.x >> 5, uspl = blockIdx.x & 31;
    int bbase = bb << 6;
    int u0 = uspl << 3;

    #pragma unroll
    for (int r = 0; r < 4; ++r) {
        int c = r * 512 + t;
        *(short8*)(Ahi + c * 8) = *(const short8*)(P23s_hi + bbase * 256 + c * 8);
    }
    p01s[t] = P01T[(u0 + (t >> 6)) * 1024 + bbase + (t & 63)];
    __syncthreads();

    int lane = t & 63;
    int wave = t >> 6;
    int wb = wave >> 2, wy = wave & 3;
    int l15 = lane & 15, l4 = lane >> 4;
    int hi8 = l4 << 3;

    int rowA0 = wb * 32 + l15;
    int swz = (rowA0 & 7) << 3;
    const short* pA0h = Ahi + rowA0 * 256;
    const short* pA1h = pA0h + 16 * 256;

    // per-wave fragment pointer: frag_id = kt*8 + yt; kt = uspl*64 + s
    const short* pf = pyF + (size_t)(uspl * 64 * 8 + wy * 2) * 512 + lane * 8;

    int y0 = wy * 32 + l15;

    const f32x4 zero4 = {0.f, 0.f, 0.f, 0.f};
    f32x4 P00 = zero4, P01v = zero4, P10 = zero4, P11 = zero4;
    bf16x8 W0, W1, X0, X1, Y0, Y1, Z0, Z1;

#define COMPUTE(CUR0, CUR1, KS)                                                  \
    {                                                                            \
        int aoff = ((KS) * 32 + hi8) ^ swz;                                      \
        bf16x8 a0h = *(const bf16x8*)(pA0h + aoff);                              \
        bf16x8 a1h = *(const bf16x8*)(pA1h + aoff);                              \
        f32x4 c00 = ((KS) == 0) ? zero4 : Q00;                                   \
        f32x4 c01 = ((KS) == 0) ? zero4 : Q01;                                   \
        f32x4 c10 = ((KS) == 0) ? zero4 : Q10;                                   \
        f32x4 c11 = ((KS) == 0) ? zero4 : Q11;                                   \
        c00 = __builtin_amdgcn_mfma_f32_16x16x32_bf16(a0h, CUR0, c00, 0, 0, 0);  \
        c10 = __builtin_amdgcn_mfma_f32_16x16x32_bf16(a1h, CUR0, c10, 0, 0, 0);  \
        c01 = __builtin_amdgcn_mfma_f32_16x16x32_bf16(a0h, CUR1, c01, 0, 0, 0);  \
        c11 = __builtin_amdgcn_mfma_f32_16x16x32_bf16(a1h, CUR1, c11, 0, 0, 0);  \
        Q00 = c00; Q01 = c01; Q10 = c10; Q11 = c11;                              \
    }

// steady step: issue frag pair for step S3 (-> 8 in flight), wait, compute
#define STEP(CUR0, CUR1, NXT0, NXT1, KS, S3)    \
    NXT0 = gload16(pf + (S3) * 4096);           \
    NXT1 = gload16(pf + (S3) * 4096 + 512);     \
    WAITV(6);                                   \
    COMPUTE(CUR0, CUR1, KS)

    {   // preload steps 0..2
        W0 = gload16(pf);        W1 = gload16(pf + 512);
        X0 = gload16(pf + 4096); X1 = gload16(pf + 4096 + 512);
        Y0 = gload16(pf + 8192); Y1 = gload16(pf + 8192 + 512);
    }

    #pragma unroll 1
    for (int uu = 0; uu < 7; ++uu) {
        int s0 = uu * 8;
        f32x4 Q00, Q01, Q10, Q11;
        STEP(W0, W1, Z0, Z1, 0, s0 + 3)
        STEP(X0, X1, W0, W1, 1, s0 + 4)
        STEP(Y0, Y1, X0, X1, 2, s0 + 5)
        STEP(Z0, Z1, Y0, Y1, 3, s0 + 6)
        STEP(W0, W1, Z0, Z1, 4, s0 + 7)
        STEP(X0, X1, W0, W1, 5, s0 + 8)
        STEP(Y0, Y1, X0, X1, 6, s0 + 9)
        STEP(Z0, Z1, Y0, Y1, 7, s0 + 10)
        f32x4 pv0 = *(const f32x4*)(p01s + uu * 64 + wb * 32 + (l4 << 2));
        f32x4 pv1 = *(const f32x4*)(p01s + uu * 64 + wb * 32 + 16 + (l4 << 2));
        P00 += pv0 * Q00; P01v += pv0 * Q01;
        P10 += pv1 * Q10; P11 += pv1 * Q11;
    }
    {   // uu = 7 peeled: steps 56..63; prefetch only while S3 <= 63
        f32x4 Q00, Q01, Q10, Q11;
        STEP(W0, W1, Z0, Z1, 0, 59)
        STEP(X0, X1, W0, W1, 1, 60)
        STEP(Y0, Y1, X0, X1, 2, 61)
        STEP(Z0, Z1, Y0, Y1, 3, 62)
        STEP(W0, W1, Z0, Z1, 4, 63)
        WAITV(4); COMPUTE(X0, X1, 5)
        WAITV(2); COMPUTE(Y0, Y1, 6)
        WAITV(0); COMPUTE(Z0, Z1, 7)
        f32x4 pv0 = *(const f32x4*)(p01s + 7 * 64 + wb * 32 + (l4 << 2));
        f32x4 pv1 = *(const f32x4*)(p01s + 7 * 64 + wb * 32 + 16 + (l4 << 2));
        P00 += pv0 * Q00; P01v += pv0 * Q01;
        P10 += pv1 * Q10; P11 += pv1 * Q11;
    }
#undef STEP
#undef COMPUTE

    size_t pbase = (size_t)uspl * 128 * 1024;
    {
        int bg0 = bbase + wb * 32 + (l4 << 2);
        int bg1 = bg0 + 16;
        *(f32x4*)(part + pbase + (size_t)y0 * 1024 + bg0) = P00;
        *(f32x4*)(part + pbase + (size_t)y0 * 1024 + bg1) = P10;
        *(f32x4*)(part + pbase + (size_t)(y0 + 16) * 1024 + bg0) = P01v;
        *(f32x4*)(part + pbase + (size_t)(y0 + 16) * 1024 + bg1) = P11;
    }
}

// ---- Kernel D: reduce 32 u-split partials -> out[b*100+y] ------------------
__global__ __launch_bounds__(256) void kD(const float* __restrict__ part,
                                          float* __restrict__ out) {
    int t = threadIdx.x;
    int y = blockIdx.x >> 2;
    int b = ((blockIdx.x & 3) << 8) + t;
    float s = 0.f;
    for (int q = 0; q < 32; ++q)
        s += part[(((size_t)q * 128 + y) << 10) + b];
    out[(size_t)b * 100 + y] = s;
}

extern "C" void kernel_launch(void* const* d_in, const int* in_sizes, int n_in,
                              void* d_out, int out_size, void* d_ws, size_t ws_size,
                              hipStream_t stream) {
    const float* logits = (const float*)d_in[0];
    const float* y_true = (const float*)d_in[1];
    float* out = (float*)d_out;

    char* ws = (char*)d_ws;
    float* P23    = (float*)(ws + (1u << 20));           // 1 MB
    float* P01T   = (float*)(ws + (2u << 20));           // 1 MB
    short* P23s_hi = (short*)(ws + (3u << 20));          // 512 KB
    int*   lab    = (int*)(ws + (4u << 20));             // 4 KB
    short* pyF    = (short*)(ws + (8u << 20));           // 16 MB fragment layout
    float* part   = (float*)(ws + (40u << 20));          // 16 MB

    kA<<<1024, 256, 0, stream>>>(logits, y_true, P23, P01T, P23s_hi, lab);
    kB<<<512, 512, 0, stream>>>(P01T, P23, lab, pyF);
    kC<<<512, 512, 0, stream>>>(P23s_hi, P01T, pyF, part);
    kD<<<400, 256, 0, stream>>>(part, out);
}

// Round 12
// 123.294 us; speedup vs baseline: 3.0747x; 3.0747x over previous
//
#include <hip/hip_runtime.h>
#include <hip/hip_bf16.h>

#define EPS 1e-6f

typedef float f32x4 __attribute__((ext_vector_type(4)));
typedef float f32x2 __attribute__((ext_vector_type(2)));
typedef __bf16 bf16x8 __attribute__((ext_vector_type(8)));
typedef short short8 __attribute__((ext_vector_type(8)));

static __device__ __forceinline__ short bf16bits(float x) {
    __hip_bfloat16 h = __float2bfloat16(x);
    short s;
    __builtin_memcpy(&s, &h, 2);
    return s;
}

// Inline-asm loads: compiler cannot sink/flatten -> counted-vmcnt pipelines
// physically exist (T4 recipe; R11 proved this works for kC).
static __device__ __forceinline__ bf16x8 gload16(const short* p) {
    bf16x8 r;
    asm volatile("global_load_dwordx4 %0, %1, off"
                 : "=&v"(r) : "v"(p) : "memory");
    return r;
}
static __device__ __forceinline__ float gloadf(const float* p) {
    float r;
    asm volatile("global_load_dword %0, %1, off"
                 : "=&v"(r) : "v"(p) : "memory");
    return r;
}
#define WAITV(N)                                                   \
    do {                                                           \
        asm volatile("s_waitcnt vmcnt(" #N ")" ::: "memory");      \
        __builtin_amdgcn_sched_barrier(0);                         \
    } while (0)

// ---- Kernel A: softmax + P23 (f32) + P01T (f32) + P23s_hi (bf16, swizzled) -
__global__ __launch_bounds__(256) void kA(const float* __restrict__ logits,
                                          const float* __restrict__ y_true,
                                          float* __restrict__ P23,
                                          float* __restrict__ P01T,
                                          short* __restrict__ P23s_hi,
                                          int* __restrict__ label) {
    __shared__ float row[64];
    int b = blockIdx.x, t = threadIdx.x;
    if (t < 64) {
        float x = logits[b * 64 + t];
        float m = x;
        for (int mk = 8; mk >= 1; mk >>= 1) m = fmaxf(m, __shfl_xor(m, mk, 16));
        float e = __expf(x - m);
        float s = e;
        for (int mk = 8; mk >= 1; mk >>= 1) s += __shfl_xor(s, mk, 16);
        row[t] = e / s;
    }
    if (t >= 128 && t < 228) {
        int y = t - 128;
        if (y_true[b * 100 + y] > 0.5f) label[b] = y;
    }
    __syncthreads();
    int hi = t >> 4, lo = t & 15;
    float v01 = row[hi] * row[16 + lo];
    float v23 = row[32 + hi] * row[48 + lo];
    P01T[t * 1024 + b] = v01;
    P23[b * 256 + t] = v23;
    int ts = t ^ ((b & 7) << 3);   // XOR swizzle (matches kC LDS read)
    P23s_hi[b * 256 + ts] = bf16bits(v23);
}

// ---- Kernel S: deterministic counting sort of b by label -------------------
__global__ __launch_bounds__(1024) void kS(const int* __restrict__ label,
                                           int* __restrict__ bidx,
                                           int* __restrict__ ylab) {
    __shared__ int lab[1024];
    __shared__ int offs[101];
    int t = threadIdx.x;
    lab[t] = label[t];
    __syncthreads();
    if (t <= 100) {
        int c = 0;
        for (int b = 0; b < 1024; ++b) c += (lab[b] < t) ? 1 : 0;
        offs[t] = c;
    }
    __syncthreads();
    int my = lab[t];
    int rank = 0;
    for (int b = 0; b < t; ++b) rank += (lab[b] == my) ? 1 : 0;
    int pos = offs[my] + rank;
    bidx[pos] = t;
    ylab[pos] = my;
}

// ---- Kernel P: pre-permute into sorted row order (kills kB's gathers) ------
__global__ __launch_bounds__(256) void kP(const float* __restrict__ P23,
                                          const float* __restrict__ P01T,
                                          const int* __restrict__ bidx,
                                          float* __restrict__ P23sort,
                                          float* __restrict__ P01Ts) {
    int bid = blockIdx.x, t = threadIdx.x;
    if (bid < 1024) {
        P23sort[bid * 256 + t] = P23[bidx[bid] * 256 + t];
    } else {
        int u = bid - 1024;
        for (int i = t; i < 1024; i += 256)
            P01Ts[u * 1024 + i] = P01T[u * 1024 + bidx[i]];   // 4KB-row gather, L1
    }
}

// ---- Kernel B: sorted segmented accumulation -> pyF (fragment layout) ------
// grid (u, colhalf) = 512 blocks x 1024 thr = 8 row-groups x 128 cols.
// All streams AFFINE (pre-permuted); asm-forced 8-deep load pipeline;
// register accumulation, LDS atomic only at y-boundaries (~13/thread).
__global__ __launch_bounds__(1024, 1) void kB(const float* __restrict__ P01Ts,
                                              const float* __restrict__ P23sort,
                                              const int* __restrict__ ylab,
                                              short* __restrict__ pyF) {
    __shared__ __align__(16) float numy[100 * 132];
    __shared__ __align__(16) float aAs[1024];
    __shared__ unsigned char yls[1024];
    __shared__ float numjl[8][128];
    int t = threadIdx.x;
    int u = blockIdx.x >> 1;
    int col0 = (blockIdx.x & 1) << 7;

    yls[t] = (unsigned char)ylab[t];
    aAs[t] = P01Ts[u * 1024 + t];       // sequential, coalesced
    for (int i = t; i < 100 * 132; i += 1024) numy[i] = 0.f;
    __syncthreads();

    int g = t >> 7, tcl = t & 127;
    int tc = col0 + tcl;
    int base = g << 7;                  // 128 rows per group
    float acc = 0.f, nj = 0.f;
    int ycur = yls[base];
    float v0, v1, v2, v3, v4, v5, v6, v7;
    float w0, w1, w2, w3, w4, w5, w6, w7;

#define LOAD8(A0, A1, A2, A3, A4, A5, A6, A7, C)                              \
    {                                                                         \
        const float* pr = P23sort + (size_t)(base + (C) * 8) * 256 + tc;      \
        A0 = gloadf(pr);        A1 = gloadf(pr + 256);                        \
        A2 = gloadf(pr + 512);  A3 = gloadf(pr + 768);                        \
        A4 = gloadf(pr + 1024); A5 = gloadf(pr + 1280);                       \
        A6 = gloadf(pr + 1536); A7 = gloadf(pr + 1792);                       \
    }
#define COMP8(A0, A1, A2, A3, A4, A5, A6, A7, C)                              \
    {                                                                         \
        int rb = base + (C) * 8;                                              \
        float va[8] = {A0, A1, A2, A3, A4, A5, A6, A7};                       \
        _Pragma("unroll")                                                     \
        for (int k = 0; k < 8; ++k) {                                         \
            int y = yls[rb + k];                                              \
            float a = aAs[rb + k];                                            \
            if (y != ycur) {                                                  \
                atomicAdd(&numy[ycur * 132 + tcl], acc);                      \
                nj += acc; acc = 0.f; ycur = y;                               \
            }                                                                 \
            acc = fmaf(a, va[k], acc);                                        \
        }                                                                     \
    }

    LOAD8(v0, v1, v2, v3, v4, v5, v6, v7, 0)
    #pragma unroll 1
    for (int cc = 0; cc < 7; ++cc) {
        LOAD8(w0, w1, w2, w3, w4, w5, w6, w7, 2 * cc + 1)
        WAITV(8);
        COMP8(v0, v1, v2, v3, v4, v5, v6, v7, 2 * cc)
        LOAD8(v0, v1, v2, v3, v4, v5, v6, v7, 2 * cc + 2)
        WAITV(8);
        COMP8(w0, w1, w2, w3, w4, w5, w6, w7, 2 * cc + 1)
    }
    LOAD8(w0, w1, w2, w3, w4, w5, w6, w7, 15)
    WAITV(8);
    COMP8(v0, v1, v2, v3, v4, v5, v6, v7, 14)
    WAITV(0);
    COMP8(w0, w1, w2, w3, w4, w5, w6, w7, 15)
#undef LOAD8
#undef COMP8

    atomicAdd(&numy[ycur * 132 + tcl], acc);
    nj += acc;
    numjl[g][tcl] = nj;
    __syncthreads();

    // fragment-layout write (same mapping as R11, 1024 threads x 8 iters)
    int c0k = col0 >> 5;                // 0 or 4
    for (int it = 0; it < 8; ++it) {
        int idx = it * 1024 + t;        // 0..8191 u32 units
        int i2 = idx & 3;
        int lane = (idx >> 2) & 63;
        int yt = (idx >> 8) & 7;
        int kt_l = idx >> 11;           // 0..3
        int l15 = lane & 15, l4 = lane >> 4;
        int y = yt * 16 + l15;
        int jl = kt_l * 32 + l4 * 8 + i2 * 2;
        float q0 = 0.f, q1 = 0.f;
        if (y < 100) {
            float d0 = 0.f, d1 = 0.f;
            #pragma unroll
            for (int gg = 0; gg < 8; ++gg) { d0 += numjl[gg][jl]; d1 += numjl[gg][jl + 1]; }
            d0 = fmaxf(d0, EPS); d1 = fmaxf(d1, EPS);
            f32x2 nv = *(const f32x2*)&numy[y * 132 + jl];
            q0 = fminf(fmaxf(nv[0], EPS) / d0, 1.0f);
            q1 = fminf(fmaxf(nv[1], EPS) / d1, 1.0f);
        }
        unsigned h0 = (unsigned short)bf16bits(q0);
        unsigned h1 = (unsigned short)bf16bits(q1);
        int kt = u * 8 + c0k + kt_l;
        size_t ei = (size_t)(kt * 8 + yt) * 256 + lane * 4 + i2;   // u32 index
        ((unsigned*)pyF)[ei] = h0 | (h1 << 16);
    }
}

// ---- Kernel C: MFMA GEMM (R11, ~14us).  part[uspl][y][b] += P01*(py x P23^T)
// A = P23 bf16 LDS (32 KB, swizzled); B = pyF fragments (contiguous 1KB/wave);
// forced asm pipeline, 4 named buffer sets, 3-step lookahead, vmcnt(6).
__global__ __launch_bounds__(512, 2) void kC(const short* __restrict__ P23s_hi,
                                             const float* __restrict__ P01T,
                                             const short* __restrict__ pyF,
                                             float* __restrict__ part) {
    __shared__ short Ahi[64 * 256];
    __shared__ float p01s[8 * 64];
    int t = threadIdx.x;
    int bb = blockIdx.x >> 5, uspl = blockIdx.x & 31;
    int bbase = bb << 6;
    int u0 = uspl << 3;

    #pragma unroll
    for (int r = 0; r < 4; ++r) {
        int c = r * 512 + t;
        *(short8*)(Ahi + c * 8) = *(const short8*)(P23s_hi + bbase * 256 + c * 8);
    }
    p01s[t] = P01T[(u0 + (t >> 6)) * 1024 + bbase + (t & 63)];
    __syncthreads();

    int lane = t & 63;
    int wave = t >> 6;
    int wb = wave >> 2, wy = wave & 3;
    int l15 = lane & 15, l4 = lane >> 4;
    int hi8 = l4 << 3;

    int rowA0 = wb * 32 + l15;
    int swz = (rowA0 & 7) << 3;
    const short* pA0h = Ahi + rowA0 * 256;
    const short* pA1h = pA0h + 16 * 256;

    const short* pf = pyF + (size_t)(uspl * 64 * 8 + wy * 2) * 512 + lane * 8;
    int y0 = wy * 32 + l15;

    const f32x4 zero4 = {0.f, 0.f, 0.f, 0.f};
    f32x4 P00 = zero4, P01v = zero4, P10 = zero4, P11 = zero4;
    bf16x8 W0, W1, X0, X1, Y0, Y1, Z0, Z1;

#define COMPUTE(CUR0, CUR1, KS)                                                  \
    {                                                                            \
        int aoff = ((KS) * 32 + hi8) ^ swz;                                      \
        bf16x8 a0h = *(const bf16x8*)(pA0h + aoff);                              \
        bf16x8 a1h = *(const bf16x8*)(pA1h + aoff);                              \
        f32x4 c00 = ((KS) == 0) ? zero4 : Q00;                                   \
        f32x4 c01 = ((KS) == 0) ? zero4 : Q01;                                   \
        f32x4 c10 = ((KS) == 0) ? zero4 : Q10;                                   \
        f32x4 c11 = ((KS) == 0) ? zero4 : Q11;                                   \
        c00 = __builtin_amdgcn_mfma_f32_16x16x32_bf16(a0h, CUR0, c00, 0, 0, 0);  \
        c10 = __builtin_amdgcn_mfma_f32_16x16x32_bf16(a1h, CUR0, c10, 0, 0, 0);  \
        c01 = __builtin_amdgcn_mfma_f32_16x16x32_bf16(a0h, CUR1, c01, 0, 0, 0);  \
        c11 = __builtin_amdgcn_mfma_f32_16x16x32_bf16(a1h, CUR1, c11, 0, 0, 0);  \
        Q00 = c00; Q01 = c01; Q10 = c10; Q11 = c11;                              \
    }
#define STEP(CUR0, CUR1, NXT0, NXT1, KS, S3)    \
    NXT0 = gload16(pf + (S3) * 4096);           \
    NXT1 = gload16(pf + (S3) * 4096 + 512);     \
    WAITV(6);                                   \
    COMPUTE(CUR0, CUR1, KS)

    {
        W0 = gload16(pf);        W1 = gload16(pf + 512);
        X0 = gload16(pf + 4096); X1 = gload16(pf + 4096 + 512);
        Y0 = gload16(pf + 8192); Y1 = gload16(pf + 8192 + 512);
    }

    #pragma unroll 1
    for (int uu = 0; uu < 7; ++uu) {
        int s0 = uu * 8;
        f32x4 Q00, Q01, Q10, Q11;
        STEP(W0, W1, Z0, Z1, 0, s0 + 3)
        STEP(X0, X1, W0, W1, 1, s0 + 4)
        STEP(Y0, Y1, X0, X1, 2, s0 + 5)
        STEP(Z0, Z1, Y0, Y1, 3, s0 + 6)
        STEP(W0, W1, Z0, Z1, 4, s0 + 7)
        STEP(X0, X1, W0, W1, 5, s0 + 8)
        STEP(Y0, Y1, X0, X1, 6, s0 + 9)
        STEP(Z0, Z1, Y0, Y1, 7, s0 + 10)
        f32x4 pv0 = *(const f32x4*)(p01s + uu * 64 + wb * 32 + (l4 << 2));
        f32x4 pv1 = *(const f32x4*)(p01s + uu * 64 + wb * 32 + 16 + (l4 << 2));
        P00 += pv0 * Q00; P01v += pv0 * Q01;
        P10 += pv1 * Q10; P11 += pv1 * Q11;
    }
    {
        f32x4 Q00, Q01, Q10, Q11;
        STEP(W0, W1, Z0, Z1, 0, 59)
        STEP(X0, X1, W0, W1, 1, 60)
        STEP(Y0, Y1, X0, X1, 2, 61)
        STEP(Z0, Z1, Y0, Y1, 3, 62)
        STEP(W0, W1, Z0, Z1, 4, 63)
        WAITV(4); COMPUTE(X0, X1, 5)
        WAITV(2); COMPUTE(Y0, Y1, 6)
        WAITV(0); COMPUTE(Z0, Z1, 7)
        f32x4 pv0 = *(const f32x4*)(p01s + 7 * 64 + wb * 32 + (l4 << 2));
        f32x4 pv1 = *(const f32x4*)(p01s + 7 * 64 + wb * 32 + 16 + (l4 << 2));
        P00 += pv0 * Q00; P01v += pv0 * Q01;
        P10 += pv1 * Q10; P11 += pv1 * Q11;
    }
#undef STEP
#undef COMPUTE

    size_t pbase = (size_t)uspl * 128 * 1024;
    {
        int bg0 = bbase + wb * 32 + (l4 << 2);
        int bg1 = bg0 + 16;
        *(f32x4*)(part + pbase + (size_t)y0 * 1024 + bg0) = P00;
        *(f32x4*)(part + pbase + (size_t)y0 * 1024 + bg1) = P10;
        *(f32x4*)(part + pbase + (size_t)(y0 + 16) * 1024 + bg0) = P01v;
        *(f32x4*)(part + pbase + (size_t)(y0 + 16) * 1024 + bg1) = P11;
    }
}

// ---- Kernel D: reduce 32 u-split partials -> out[b*100+y] ------------------
__global__ __launch_bounds__(256) void kD(const float* __restrict__ part,
                                          float* __restrict__ out) {
    int t = threadIdx.x;
    int y = blockIdx.x >> 2;
    int b = ((blockIdx.x & 3) << 8) + t;
    float s = 0.f;
    for (int q = 0; q < 32; ++q)
        s += part[(((size_t)q * 128 + y) << 10) + b];
    out[(size_t)b * 100 + y] = s;
}

extern "C" void kernel_launch(void* const* d_in, const int* in_sizes, int n_in,
                              void* d_out, int out_size, void* d_ws, size_t ws_size,
                              hipStream_t stream) {
    const float* logits = (const float*)d_in[0];
    const float* y_true = (const float*)d_in[1];
    float* out = (float*)d_out;

    char* ws = (char*)d_ws;
    float* P23     = (float*)(ws + (1u << 20));          // 1 MB
    float* P01T    = (float*)(ws + (2u << 20));          // 1 MB
    short* P23s_hi = (short*)(ws + (3u << 20));          // 512 KB
    int*   lab     = (int*)(ws + (4u << 20));            // 4 KB
    int*   bidx    = (int*)(ws + (4u << 20) + 4096);
    int*   ylab    = (int*)(ws + (4u << 20) + 8192);
    float* P23sort = (float*)(ws + (5u << 20));          // 1 MB
    float* P01Ts   = (float*)(ws + (6u << 20));          // 1 MB
    short* pyF     = (short*)(ws + (8u << 20));          // 16 MB fragment layout
    float* part    = (float*)(ws + (40u << 20));         // 16 MB

    kA<<<1024, 256, 0, stream>>>(logits, y_true, P23, P01T, P23s_hi, lab);
    kS<<<1, 1024, 0, stream>>>(lab, bidx, ylab);
    kP<<<1280, 256, 0, stream>>>(P23, P01T, bidx, P23sort, P01Ts);
    kB<<<512, 1024, 0, stream>>>(P01Ts, P23sort, ylab, pyF);
    kC<<<512, 512, 0, stream>>>(P23s_hi, P01T, pyF, part);
    kD<<<400, 256, 0, stream>>>(part, out);
}

// Round 13
// 113.780 us; speedup vs baseline: 3.3318x; 1.0836x over previous
//
#include <hip/hip_runtime.h>
#include <hip/hip_bf16.h>

#define EPS 1e-6f

typedef float f32x4 __attribute__((ext_vector_type(4)));
typedef float f32x2 __attribute__((ext_vector_type(2)));
typedef __bf16 bf16x8 __attribute__((ext_vector_type(8)));
typedef short short8 __attribute__((ext_vector_type(8)));

static __device__ __forceinline__ short bf16bits(float x) {
    __hip_bfloat16 h = __float2bfloat16(x);
    short s;
    __builtin_memcpy(&s, &h, 2);
    return s;
}

// Inline-asm loads for kC only (forced counted-vmcnt pipeline, proven R11).
static __device__ __forceinline__ bf16x8 gload16(const short* p) {
    bf16x8 r;
    asm volatile("global_load_dwordx4 %0, %1, off"
                 : "=&v"(r) : "v"(p) : "memory");
    return r;
}
#define WAITV(N)                                                   \
    do {                                                           \
        asm volatile("s_waitcnt vmcnt(" #N ")" ::: "memory");      \
        __builtin_amdgcn_sched_barrier(0);                         \
    } while (0)

// ---- Kernel A: softmax + P23 (f32) + P01T (f32) + P23s_hi (bf16, swizzled) -
__global__ __launch_bounds__(256) void kA(const float* __restrict__ logits,
                                          const float* __restrict__ y_true,
                                          float* __restrict__ P23,
                                          float* __restrict__ P01T,
                                          short* __restrict__ P23s_hi,
                                          int* __restrict__ label) {
    __shared__ float row[64];
    int b = blockIdx.x, t = threadIdx.x;
    if (t < 64) {
        float x = logits[b * 64 + t];
        float m = x;
        for (int mk = 8; mk >= 1; mk >>= 1) m = fmaxf(m, __shfl_xor(m, mk, 16));
        float e = __expf(x - m);
        float s = e;
        for (int mk = 8; mk >= 1; mk >>= 1) s += __shfl_xor(s, mk, 16);
        row[t] = e / s;
    }
    if (t >= 128 && t < 228) {
        int y = t - 128;
        if (y_true[b * 100 + y] > 0.5f) label[b] = y;
    }
    __syncthreads();
    int hi = t >> 4, lo = t & 15;
    float v01 = row[hi] * row[16 + lo];
    float v23 = row[32 + hi] * row[48 + lo];
    P01T[t * 1024 + b] = v01;
    P23[b * 256 + t] = v23;
    int ts = t ^ ((b & 7) << 3);   // XOR swizzle (matches kC LDS read)
    P23s_hi[b * 256 + ts] = bf16bits(v23);
}

// ---- Kernel S: deterministic counting sort of b by label -------------------
__global__ __launch_bounds__(1024) void kS(const int* __restrict__ label,
                                           int* __restrict__ bidx,
                                           int* __restrict__ ylab) {
    __shared__ int lab[1024];
    __shared__ int offs[101];
    int t = threadIdx.x;
    lab[t] = label[t];
    __syncthreads();
    if (t <= 100) {
        int c = 0;
        for (int b = 0; b < 1024; ++b) c += (lab[b] < t) ? 1 : 0;
        offs[t] = c;
    }
    __syncthreads();
    int my = lab[t];
    int rank = 0;
    for (int b = 0; b < t; ++b) rank += (lab[b] == my) ? 1 : 0;
    int pos = offs[my] + rank;
    bidx[pos] = t;
    ylab[pos] = my;
}

// ---- Kernel P: pre-permute into sorted row order (kills kB's gathers) ------
__global__ __launch_bounds__(256) void kP(const float* __restrict__ P23,
                                          const float* __restrict__ P01T,
                                          const int* __restrict__ bidx,
                                          float* __restrict__ P23sort,
                                          float* __restrict__ P01Ts) {
    int bid = blockIdx.x, t = threadIdx.x;
    if (bid < 1024) {
        P23sort[bid * 256 + t] = P23[bidx[bid] * 256 + t];
    } else {
        int u = bid - 1024;
        for (int i = t; i < 1024; i += 256)
            P01Ts[u * 1024 + i] = P01T[u * 1024 + bidx[i]];   // 4KB-row gather, L1
    }
}

// ---- Kernel B: sorted segmented accumulation -> pyF (fragment layout) ------
// grid (u, colhalf) = 512 blocks x 1024 thr = 8 groups x 128 cols.
// Per thread: 2 independent 64-row streams (A/B). Segment boundaries as
// per-wave 64-bit ballot masks; fast path (no boundary in chunk) is pure
// 8x fmaf with f32x4 aAs reads. Plain affine loads (compiler batches).
__global__ __launch_bounds__(1024, 1) void kB(const float* __restrict__ P01Ts,
                                              const float* __restrict__ P23sort,
                                              const int* __restrict__ ylab,
                                              short* __restrict__ pyF) {
    __shared__ __align__(16) float numy[100 * 132];
    __shared__ __align__(16) float aAs[1024];
    __shared__ unsigned char yls[1024];
    __shared__ float numjl[8][128];
    __shared__ unsigned long long bmaskL[16];
    int t = threadIdx.x;
    int u = blockIdx.x >> 1;
    int col0 = (blockIdx.x & 1) << 7;

    yls[t] = (unsigned char)ylab[t];
    aAs[t] = P01Ts[u * 1024 + t];       // sequential, coalesced
    for (int i = t; i < 100 * 132; i += 1024) numy[i] = 0.f;
    __syncthreads();
    {
        unsigned long long m = __ballot(t > 0 && yls[t] != yls[t - 1]);
        if ((t & 63) == 0) bmaskL[t >> 6] = m;
    }
    __syncthreads();

    int g = t >> 7, tcl = t & 127;
    int tc = col0 + tcl;
    int baseA = g << 7;                 // stream A rows baseA..+63
    int baseB = baseA + 64;             // stream B rows baseB..+63
    unsigned long long mA = bmaskL[2 * g], mB = bmaskL[2 * g + 1];
    const float* pA = P23sort + (size_t)baseA * 256 + tc;
    const float* pB = P23sort + (size_t)baseB * 256 + tc;

    float accA = 0.f, accB = 0.f, nj = 0.f;
    int ycA = yls[baseA], ycB = yls[baseB];

    #pragma unroll 1
    for (int c = 0; c < 8; ++c) {
        float lA[8], lB[8];
        #pragma unroll
        for (int k = 0; k < 8; ++k) lA[k] = pA[(c * 8 + k) * 256];
        #pragma unroll
        for (int k = 0; k < 8; ++k) lB[k] = pB[(c * 8 + k) * 256];
        int rbA = baseA + c * 8, rbB = baseB + c * 8;
        f32x4 aA0 = *(const f32x4*)&aAs[rbA];
        f32x4 aA1 = *(const f32x4*)&aAs[rbA + 4];
        f32x4 aB0 = *(const f32x4*)&aAs[rbB];
        f32x4 aB1 = *(const f32x4*)&aAs[rbB + 4];
        unsigned mAc = (unsigned)(mA >> (c * 8)) & 255u;
        unsigned mBc = (unsigned)(mB >> (c * 8)) & 255u;
        if (mAc == 0) {
            #pragma unroll
            for (int k = 0; k < 8; ++k)
                accA = fmaf((k < 4) ? aA0[k] : aA1[k - 4], lA[k], accA);
        } else {
            #pragma unroll
            for (int k = 0; k < 8; ++k) {
                if (mAc & (1u << k)) {
                    atomicAdd(&numy[ycA * 132 + tcl], accA);
                    nj += accA; accA = 0.f;
                    ycA = yls[rbA + k];
                }
                accA = fmaf((k < 4) ? aA0[k] : aA1[k - 4], lA[k], accA);
            }
        }
        if (mBc == 0) {
            #pragma unroll
            for (int k = 0; k < 8; ++k)
                accB = fmaf((k < 4) ? aB0[k] : aB1[k - 4], lB[k], accB);
        } else {
            #pragma unroll
            for (int k = 0; k < 8; ++k) {
                if (mBc & (1u << k)) {
                    atomicAdd(&numy[ycB * 132 + tcl], accB);
                    nj += accB; accB = 0.f;
                    ycB = yls[rbB + k];
                }
                accB = fmaf((k < 4) ? aB0[k] : aB1[k - 4], lB[k], accB);
            }
        }
    }
    atomicAdd(&numy[ycA * 132 + tcl], accA); nj += accA;
    atomicAdd(&numy[ycB * 132 + tcl], accB); nj += accB;
    numjl[g][tcl] = nj;
    __syncthreads();

    // fragment-layout write (verified R11/R12)
    int c0k = col0 >> 5;                // 0 or 4
    for (int it = 0; it < 8; ++it) {
        int idx = it * 1024 + t;        // 0..8191 u32 units
        int i2 = idx & 3;
        int lane = (idx >> 2) & 63;
        int yt = (idx >> 8) & 7;
        int kt_l = idx >> 11;           // 0..3
        int l15 = lane & 15, l4 = lane >> 4;
        int y = yt * 16 + l15;
        int jl = kt_l * 32 + l4 * 8 + i2 * 2;
        float q0 = 0.f, q1 = 0.f;
        if (y < 100) {
            float d0 = 0.f, d1 = 0.f;
            #pragma unroll
            for (int gg = 0; gg < 8; ++gg) { d0 += numjl[gg][jl]; d1 += numjl[gg][jl + 1]; }
            d0 = fmaxf(d0, EPS); d1 = fmaxf(d1, EPS);
            f32x2 nv = *(const f32x2*)&numy[y * 132 + jl];
            q0 = fminf(fmaxf(nv[0], EPS) / d0, 1.0f);
            q1 = fminf(fmaxf(nv[1], EPS) / d1, 1.0f);
        }
        unsigned h0 = (unsigned short)bf16bits(q0);
        unsigned h1 = (unsigned short)bf16bits(q1);
        int kt = u * 8 + c0k + kt_l;
        size_t ei = (size_t)(kt * 8 + yt) * 256 + lane * 4 + i2;   // u32 index
        ((unsigned*)pyF)[ei] = h0 | (h1 << 16);
    }
}

// ---- Kernel C: MFMA GEMM (R11, ~14us, L2-floor).  part += P01*(py x P23^T) -
__global__ __launch_bounds__(512, 2) void kC(const short* __restrict__ P23s_hi,
                                             const float* __restrict__ P01T,
                                             const short* __restrict__ pyF,
                                             float* __restrict__ part) {
    __shared__ short Ahi[64 * 256];
    __shared__ float p01s[8 * 64];
    int t = threadIdx.x;
    int bb = blockIdx.x >> 5, uspl = blockIdx.x & 31;
    int bbase = bb << 6;
    int u0 = uspl << 3;

    #pragma unroll
    for (int r = 0; r < 4; ++r) {
        int c = r * 512 + t;
        *(short8*)(Ahi + c * 8) = *(const short8*)(P23s_hi + bbase * 256 + c * 8);
    }
    p01s[t] = P01T[(u0 + (t >> 6)) * 1024 + bbase + (t & 63)];
    __syncthreads();

    int lane = t & 63;
    int wave = t >> 6;
    int wb = wave >> 2, wy = wave & 3;
    int l15 = lane & 15, l4 = lane >> 4;
    int hi8 = l4 << 3;

    int rowA0 = wb * 32 + l15;
    int swz = (rowA0 & 7) << 3;
    const short* pA0h = Ahi + rowA0 * 256;
    const short* pA1h = pA0h + 16 * 256;

    const short* pf = pyF + (size_t)(uspl * 64 * 8 + wy * 2) * 512 + lane * 8;
    int y0 = wy * 32 + l15;

    const f32x4 zero4 = {0.f, 0.f, 0.f, 0.f};
    f32x4 P00 = zero4, P01v = zero4, P10 = zero4, P11 = zero4;
    bf16x8 W0, W1, X0, X1, Y0, Y1, Z0, Z1;

#define COMPUTE(CUR0, CUR1, KS)                                                  \
    {                                                                            \
        int aoff = ((KS) * 32 + hi8) ^ swz;                                      \
        bf16x8 a0h = *(const bf16x8*)(pA0h + aoff);                              \
        bf16x8 a1h = *(const bf16x8*)(pA1h + aoff);                              \
        f32x4 c00 = ((KS) == 0) ? zero4 : Q00;                                   \
        f32x4 c01 = ((KS) == 0) ? zero4 : Q01;                                   \
        f32x4 c10 = ((KS) == 0) ? zero4 : Q10;                                   \
        f32x4 c11 = ((KS) == 0) ? zero4 : Q11;                                   \
        c00 = __builtin_amdgcn_mfma_f32_16x16x32_bf16(a0h, CUR0, c00, 0, 0, 0);  \
        c10 = __builtin_amdgcn_mfma_f32_16x16x32_bf16(a1h, CUR0, c10, 0, 0, 0);  \
        c01 = __builtin_amdgcn_mfma_f32_16x16x32_bf16(a0h, CUR1, c01, 0, 0, 0);  \
        c11 = __builtin_amdgcn_mfma_f32_16x16x32_bf16(a1h, CUR1, c11, 0, 0, 0);  \
        Q00 = c00; Q01 = c01; Q10 = c10; Q11 = c11;                              \
    }
#define STEP(CUR0, CUR1, NXT0, NXT1, KS, S3)    \
    NXT0 = gload16(pf + (S3) * 4096);           \
    NXT1 = gload16(pf + (S3) * 4096 + 512);     \
    WAITV(6);                                   \
    COMPUTE(CUR0, CUR1, KS)

    {
        W0 = gload16(pf);        W1 = gload16(pf + 512);
        X0 = gload16(pf + 4096); X1 = gload16(pf + 4096 + 512);
        Y0 = gload16(pf + 8192); Y1 = gload16(pf + 8192 + 512);
    }

    #pragma unroll 1
    for (int uu = 0; uu < 7; ++uu) {
        int s0 = uu * 8;
        f32x4 Q00, Q01, Q10, Q11;
        STEP(W0, W1, Z0, Z1, 0, s0 + 3)
        STEP(X0, X1, W0, W1, 1, s0 + 4)
        STEP(Y0, Y1, X0, X1, 2, s0 + 5)
        STEP(Z0, Z1, Y0, Y1, 3, s0 + 6)
        STEP(W0, W1, Z0, Z1, 4, s0 + 7)
        STEP(X0, X1, W0, W1, 5, s0 + 8)
        STEP(Y0, Y1, X0, X1, 6, s0 + 9)
        STEP(Z0, Z1, Y0, Y1, 7, s0 + 10)
        f32x4 pv0 = *(const f32x4*)(p01s + uu * 64 + wb * 32 + (l4 << 2));
        f32x4 pv1 = *(const f32x4*)(p01s + uu * 64 + wb * 32 + 16 + (l4 << 2));
        P00 += pv0 * Q00; P01v += pv0 * Q01;
        P10 += pv1 * Q10; P11 += pv1 * Q11;
    }
    {
        f32x4 Q00, Q01, Q10, Q11;
        STEP(W0, W1, Z0, Z1, 0, 59)
        STEP(X0, X1, W0, W1, 1, 60)
        STEP(Y0, Y1, X0, X1, 2, 61)
        STEP(Z0, Z1, Y0, Y1, 3, 62)
        STEP(W0, W1, Z0, Z1, 4, 63)
        WAITV(4); COMPUTE(X0, X1, 5)
        WAITV(2); COMPUTE(Y0, Y1, 6)
        WAITV(0); COMPUTE(Z0, Z1, 7)
        f32x4 pv0 = *(const f32x4*)(p01s + 7 * 64 + wb * 32 + (l4 << 2));
        f32x4 pv1 = *(const f32x4*)(p01s + 7 * 64 + wb * 32 + 16 + (l4 << 2));
        P00 += pv0 * Q00; P01v += pv0 * Q01;
        P10 += pv1 * Q10; P11 += pv1 * Q11;
    }
#undef STEP
#undef COMPUTE

    size_t pbase = (size_t)uspl * 128 * 1024;
    {
        int bg0 = bbase + wb * 32 + (l4 << 2);
        int bg1 = bg0 + 16;
        *(f32x4*)(part + pbase + (size_t)y0 * 1024 + bg0) = P00;
        *(f32x4*)(part + pbase + (size_t)y0 * 1024 + bg1) = P10;
        *(f32x4*)(part + pbase + (size_t)(y0 + 16) * 1024 + bg0) = P01v;
        *(f32x4*)(part + pbase + (size_t)(y0 + 16) * 1024 + bg1) = P11;
    }
}

// ---- Kernel D: reduce 32 u-split partials -> out[b*100+y] ------------------
__global__ __launch_bounds__(256) void kD(const float* __restrict__ part,
                                          float* __restrict__ out) {
    int t = threadIdx.x;
    int y = blockIdx.x >> 2;
    int b = ((blockIdx.x & 3) << 8) + t;
    float s = 0.f;
    for (int q = 0; q < 32; ++q)
        s += part[(((size_t)q * 128 + y) << 10) + b];
    out[(size_t)b * 100 + y] = s;
}

extern "C" void kernel_launch(void* const* d_in, const int* in_sizes, int n_in,
                              void* d_out, int out_size, void* d_ws, size_t ws_size,
                              hipStream_t stream) {
    const float* logits = (const float*)d_in[0];
    const float* y_true = (const float*)d_in[1];
    float* out = (float*)d_out;

    char* ws = (char*)d_ws;
    float* P23     = (float*)(ws + (1u << 20));          // 1 MB
    float* P01T    = (float*)(ws + (2u << 20));          // 1 MB
    short* P23s_hi = (short*)(ws + (3u << 20));          // 512 KB
    int*   lab     = (int*)(ws + (4u << 20));            // 4 KB
    int*   bidx    = (int*)(ws + (4u << 20) + 4096);
    int*   ylab    = (int*)(ws + (4u << 20) + 8192);
    float* P23sort = (float*)(ws + (5u << 20));          // 1 MB
    float* P01Ts   = (float*)(ws + (6u << 20));          // 1 MB
    short* pyF     = (short*)(ws + (8u << 20));          // 16 MB fragment layout
    float* part    = (float*)(ws + (40u << 20));         // 16 MB

    kA<<<1024, 256, 0, stream>>>(logits, y_true, P23, P01T, P23s_hi, lab);
    kS<<<1, 1024, 0, stream>>>(lab, bidx, ylab);
    kP<<<1280, 256, 0, stream>>>(P23, P01T, bidx, P23sort, P01Ts);
    kB<<<512, 1024, 0, stream>>>(P01Ts, P23sort, ylab, pyF);
    kC<<<512, 512, 0, stream>>>(P23s_hi, P01T, pyF, part);
    kD<<<400, 256, 0, stream>>>(part, out);
}